// Round 9
// baseline (242.124 us; speedup 1.0000x reference)
//
#include <hip/hip_runtime.h>
#include <math.h>

#define Bx 256
#define Nx 128
#define Dx 512
#define NTYPES 6
#define NSTATS 8
#define LN_EPS 1e-5f
#define CAP 8192          // max compacted masked rows (true ~4915)

typedef __attribute__((ext_vector_type(8))) short frag8;   // 8 bf16 (4 VGPRs)
typedef __attribute__((ext_vector_type(4))) float f32x4;   // 4 fp32 acc

__device__ __forceinline__ unsigned short f2bf(float f) {
    unsigned u = __float_as_uint(f);
    u += 0x7fff + ((u >> 16) & 1);   // RNE
    return (unsigned short)(u >> 16);
}
__device__ __forceinline__ float bf2f(unsigned short s) {
    return __uint_as_float((unsigned)s << 16);
}

#define ASYNC16(g, l) __builtin_amdgcn_global_load_lds(                      \
    (const __attribute__((address_space(1))) void*)(g),                      \
    (__attribute__((address_space(3))) void*)(l), 16, 0, 0)

#define VWAIT(NIMM)                                                          \
    asm volatile("s_waitcnt vmcnt(" #NIMM ")" ::: "memory");                 \
    __builtin_amdgcn_sched_barrier(0);
#define BARX __builtin_amdgcn_s_barrier();

// ws layout (bytes)
#define EB_OFF    0ULL          // Eb  bf16 [32768][512]   32 MB
#define HC_OFF    33554432ULL   // Hc  bf16 [CAP][2048]    32 MB (heads|U_m|V_m)
#define WT_OFF    67108864ULL   // Wtcmb bf16 [1024][512]   1 MB
#define WTC_OFF   68157440ULL   // Wtc bf16 [512][512]    0.5 MB (= cW^T rows)
#define WC_OFF    68681728ULL   // Wc  bf16 [512][512]    0.5 MB (= cW rows)
#define LIST_OFF  69206016ULL   // int[CAP]
#define CNTS_OFF  69238784ULL   // int[256]
#define BASES_OFF 69239808ULL   // int[256]
#define CNTP_OFF  69240832ULL   // int   (memset region starts here, 48 B)
#define ACC_OFF   69240848ULL   // float[4]: CE, SSE, CO, ME
#define DONE_OFF  69240864ULL   // int arrival counter

// Mega-prep, one dispatch:
// blocks [0,256):    per-batch mask compaction -> list/cnts/bases/cntp
// blocks [256,448):  3 weight transposes via coalesced LDS 64x64 tiles
// blocks [448,512):  straight convert cW f32 -> bf16 row-major (Wc)
// blocks [512,8704): E f32 -> bf16 (wave per row, 4 rows/block)
__global__ __launch_bounds__(256) void k_prep(
    const float* __restrict__ e, const float* __restrict__ W0,
    const float* __restrict__ W1, const float* __restrict__ W2,
    unsigned short* __restrict__ Eb, unsigned short* __restrict__ Tcmb,
    unsigned short* __restrict__ Tc, unsigned short* __restrict__ Wc,
    const int* __restrict__ m, int* __restrict__ list,
    int* __restrict__ cnts, int* __restrict__ bases, int* cntp) {
    const int bid = blockIdx.x;
    const int t = threadIdx.x;
    if (bid < 256) {
        const int b = bid;
        const int r = b * Nx + t;
        int v = 0;
        if (t < 128) v = (m[r] != 0) ? 1 : 0;
        const unsigned long long bal = __ballot(v);
        const int wid = t >> 6, lane = t & 63;
        __shared__ int wcnt[2];
        __shared__ int base;
        if (lane == 0 && wid < 2) wcnt[wid] = __popcll(bal);
        __syncthreads();
        const int cnt = wcnt[0] + wcnt[1];
        if (t == 0) {
            base = atomicAdd(cntp, cnt);
            cnts[b] = cnt;
            bases[b] = base;
        }
        __syncthreads();
        if (t < 128 && v) {
            const int rank = __popcll(bal & ((1ULL << lane) - 1)) +
                             (wid ? wcnt[0] : 0);
            const int p = base + rank;
            if (p < CAP) list[p] = r;
        }
        return;
    }
    if (bid < 448) {
        const int lin = bid - 256;          // 0..191
        const int mid = lin >> 6;           // matrix 0..2 (tW1, sW1, cW)
        const int tl  = lin & 63;
        const int ti = tl >> 3, tj = tl & 7;
        const float* W = (mid == 0) ? W0 : (mid == 1) ? W1 : W2;
        unsigned short* T = (mid == 2) ? Tc : (Tcmb + mid * 262144);
        __shared__ float sh[64][65];
        const int c = t & 63;
        const int r4 = t >> 6;
#pragma unroll
        for (int rr = 0; rr < 16; ++rr) {
            const int row = rr * 4 + r4;
            sh[row][c] = W[(size_t)(ti * 64 + row) * Dx + tj * 64 + c];
        }
        __syncthreads();
#pragma unroll
        for (int rr = 0; rr < 16; ++rr) {
            const int col2 = rr * 4 + r4;
            T[(size_t)(tj * 64 + col2) * Dx + ti * 64 + c] = f2bf(sh[c][col2]);
        }
        return;
    }
    if (bid < 512) {
        // cW f32 -> bf16 row-major (B-rows for V_m = E @ cW^T)
        const int base = (bid - 448) * 4096 + t * 16;
        const float4* src = (const float4*)(W2 + base);
        unsigned short o[16];
#pragma unroll
        for (int q = 0; q < 4; ++q) {
            const float4 v = src[q];
            o[q * 4 + 0] = f2bf(v.x); o[q * 4 + 1] = f2bf(v.y);
            o[q * 4 + 2] = f2bf(v.z); o[q * 4 + 3] = f2bf(v.w);
        }
        *(uint4*)(Wc + base) = *(const uint4*)(o);
        *(uint4*)(Wc + base + 8) = *(const uint4*)(o + 8);
        return;
    }
    const int r = (bid - 512) * 4 + (t >> 6);
    const int lane = t & 63;
    const float4* src = (const float4*)(e + (size_t)r * Dx);
    const float4 a = src[lane * 2];
    const float4 b = src[lane * 2 + 1];
    unsigned short u[8] = {f2bf(a.x), f2bf(a.y), f2bf(a.z), f2bf(a.w),
                           f2bf(b.x), f2bf(b.y), f2bf(b.z), f2bf(b.w)};
    ((uint4*)(Eb + (size_t)r * Dx))[lane] = *(const uint4*)u;
}

// Combined masked GEMM: Hc[pos][0:2048] =
//   [ GELU(E[list[pos]] @ Wtcmb^T + bias) | E[list] @ cW | E[list] @ cW^T ]
// 128x256 tiles, 512 threads (8 waves of 64x64), BK=32, counted-vmcnt dbuf.
__global__ __launch_bounds__(512) void k_gemms(
    const unsigned short* __restrict__ Eb,
    const unsigned short* __restrict__ Wtcmb,
    const unsigned short* __restrict__ Wtc,
    const unsigned short* __restrict__ Wc,
    const float* __restrict__ bias0, const float* __restrict__ bias1,
    unsigned short* __restrict__ Hc,
    const int* __restrict__ list, const int* __restrict__ cntp) {
    __shared__ unsigned short As[2 * 4096];   // 2 x [128][32] bf16
    __shared__ unsigned short Bs[2 * 8192];   // 2 x [256][32] bf16
    const int bid = blockIdx.x;
    const int t = threadIdx.x;
    const int cnt = min(*cntp, CAP);
    const int rt = ((bid >> 6) << 3) | (bid & 7);   // XCD-swizzled row tile
    const int row0 = rt << 7;
    if (row0 >= cnt) return;
    const int ct = (bid >> 3) & 7;
    const int col0 = ct << 8;
    // Bbase already includes the 256-col panel offset.
    const unsigned short* Bbase =
        (ct < 4) ? (Wtcmb + (size_t)ct * 256 * Dx)
      : (ct < 6) ? (Wtc + (size_t)(ct - 4) * 256 * Dx)
                 : (Wc + (size_t)(ct - 6) * 256 * Dx);
    const int kq = (t & 3) ^ ((t >> 3) & 3);
    const int ra = list[min(row0 + (t >> 2), cnt - 1)];
    const unsigned short* pA = Eb + (size_t)ra * Dx + kq * 8;
    const unsigned short* pB0 = Bbase + (size_t)(t >> 2) * Dx + kq * 8;
    const unsigned short* pB1 = pB0 + (size_t)128 * Dx;
    const int w = t >> 6, l = t & 63;
    const int wr = (w >> 2) * 64, wcol = (w & 3) * 64;
    const int quad = l >> 4, mr = l & 15;
    const int co = (quad ^ ((mr >> 1) & 3)) * 8;

#define MSTAGE(bf, k0)                                                       \
  { ASYNC16(pA + (k0), As + (bf) * 4096 + t * 8);                            \
    ASYNC16(pB0 + (k0), Bs + (bf) * 8192 + t * 8);                           \
    ASYNC16(pB1 + (k0), Bs + (bf) * 8192 + 4096 + t * 8); }

    f32x4 acc[4][4] = {};
    MSTAGE(0, 0);
    int buf = 0;
    for (int k = 0; k < 16; ++k) {
        if (k < 15) { MSTAGE(buf ^ 1, (k + 1) * 32); VWAIT(3); }
        else        { VWAIT(0); }
        BARX;
        frag8 af[4], bfv[4];
#pragma unroll
        for (int i = 0; i < 4; ++i)
            af[i] = *(const frag8*)&As[buf * 4096 + (wr + i * 16 + mr) * 32 + co];
#pragma unroll
        for (int j = 0; j < 4; ++j)
            bfv[j] = *(const frag8*)&Bs[buf * 8192 + (wcol + j * 16 + mr) * 32 + co];
        __builtin_amdgcn_s_setprio(1);
#pragma unroll
        for (int i = 0; i < 4; ++i)
#pragma unroll
            for (int j = 0; j < 4; ++j)
                acc[i][j] = __builtin_amdgcn_mfma_f32_16x16x32_bf16(
                    af[i], bfv[j], acc[i][j], 0, 0, 0);
        __builtin_amdgcn_s_setprio(0);
        if (k < 15) BARX;
        buf ^= 1;
    }
#pragma unroll
    for (int i = 0; i < 4; ++i)
#pragma unroll
        for (int j = 0; j < 4; ++j)
#pragma unroll
            for (int r = 0; r < 4; ++r) {
                const int row = row0 + wr + i * 16 + quad * 4 + r;
                const int col = col0 + wcol + j * 16 + mr;
                float v = acc[i][j][r];
                if (col < 1024) {
                    v += (col < 512) ? bias0[col] : bias1[col - 512];
                    v = 0.5f * v * (1.0f + erff(v * 0.70710678118654752f));
                }
                Hc[(size_t)row * 2048 + col] = f2bf(v);
            }
#undef MSTAGE
}

// Tail, one dispatch (grid 768):
// blocks [0,512):   corr, one (batch, output-half) each: block (b,h) computes
//                   T1 for j in half h and T2 for i in half h. E staged 64
//                   rows/block (4KB/iter), U/V chunked 32 rows. 3-buffer
//                   depth-2 counted-vmcnt pipeline.
// blocks [512,768): MLP heads: LN + W2 + CE/MSE over compact list
__global__ __launch_bounds__(256) void k_tail(
    const unsigned short* __restrict__ Eb,
    const float* __restrict__ Ct, const int* __restrict__ m,
    const float* __restrict__ cbp,
    const unsigned short* __restrict__ Hc,
    const float* __restrict__ tg, const float* __restrict__ tbeta,
    const float* __restrict__ tW2, const float* __restrict__ tb2,
    const float* __restrict__ sg, const float* __restrict__ sbeta,
    const float* __restrict__ sW2, const float* __restrict__ sb2,
    const int* __restrict__ list, const int* __restrict__ cnts,
    const int* __restrict__ bases, const int* __restrict__ cntp,
    const int* __restrict__ tgt, const float* __restrict__ stats,
    float* __restrict__ accs, int* __restrict__ done,
    float* __restrict__ out) {
    __shared__ unsigned short Elds[3 * 2048];   // 3 x [64][32] bf16
    __shared__ unsigned short Ulds[3 * 1024];   // 3 x [32][32] bf16
    __shared__ unsigned short Vlds[3 * 1024];
    __shared__ float mloc[128];
    __shared__ int lrow[128];
    __shared__ float redf[4][2];
    const int t = threadIdx.x;
    const int w = t >> 6, l = t & 63;
    const int quad = l >> 4, mr = l & 15;

    if (blockIdx.x < 512) {
        const int b = blockIdx.x >> 1;
        const int h = blockIdx.x & 1;            // output half: rows/cols h*64..
        const int cnt = cnts[b];
        const int cbase = bases[b];
        if (t < 128) {
            mloc[t] = (m[b * Nx + t] != 0) ? 1.0f : 0.0f;
            lrow[t] = (t < cnt) ? (list[cbase + t] & (Nx - 1)) : 0;
        }
        __syncthreads();
        float T1 = 0.0f, T2 = 0.0f, Tov = 0.0f;
        const float cb = cbp[0];
        const float* Ctb = Ct + (size_t)b * Nx * Nx;
        if (cnt > 0) {
            // E tile [64][32] bf16 (rows h*64..h*64+63): 1 load/thread,
            // row = t>>2, slot t&3 holds global chunk (t&3)^((row>>1)&3)
            const int kq = (t & 3) ^ ((t >> 3) & 3);
            const size_t rb = (size_t)b * Nx + h * 64;
            const unsigned short* pE = Eb + (rb + (t >> 2)) * Dx + kq * 8;
            // U/V tile [32][32]: waves 0-1 stage U, waves 2-3 stage V
            const int hw = t >> 7;
            const int t2 = t & 127;
            const int kq2 = (t2 & 3) ^ ((t2 >> 3) & 3);
            const int co = (quad ^ ((mr >> 1) & 3)) * 8;

            for (int c0 = 0; c0 < cnt; c0 += 32) {
                const int ntc = min(((cnt - c0) + 15) >> 4, 2);
                const int urow = min(c0 + (t2 >> 2), cnt - 1);
                const unsigned short* pUV = Hc + (size_t)(cbase + urow) * 2048
                                            + (hw ? 1536 : 1024) + kq2 * 8;
                unsigned short* UVdst = hw ? Vlds : Ulds;

#define TSTAGE(bf, ph)                                                       \
  { ASYNC16(pE + (ph) * 32, Elds + (bf) * 2048 + t * 8);                     \
    ASYNC16(pUV + (ph) * 32, UVdst + (bf) * 1024 + t2 * 8); }

                f32x4 ar[2] = {};   // T1: [masked i-tile], j = wave's frag
                f32x4 ac[2] = {};   // T2: i = wave's frag, [masked j-tile]
                TSTAGE(0, 0); TSTAGE(1, 1);
                for (int k = 0; k < 16; ++k) {
                    if (k < 15) { VWAIT(2); } else { VWAIT(0); }
                    BARX;
                    if (k < 14) TSTAGE((k + 2) % 3, k + 2);
                    const int buf = k % 3;
                    const frag8 ef = *(const frag8*)&Elds[buf * 2048 +
                        (w * 16 + mr) * 32 + co];
                    __builtin_amdgcn_s_setprio(1);
#pragma unroll
                    for (int it = 0; it < 2; ++it)
                        if (it < ntc) {
                            const frag8 uf = *(const frag8*)&Ulds[buf * 1024 +
                                (it * 16 + mr) * 32 + co];
                            ar[it] = __builtin_amdgcn_mfma_f32_16x16x32_bf16(
                                uf, ef, ar[it], 0, 0, 0);
                        }
#pragma unroll
                    for (int jt = 0; jt < 2; ++jt)
                        if (jt < ntc) {
                            const frag8 vf = *(const frag8*)&Vlds[buf * 1024 +
                                (jt * 16 + mr) * 32 + co];
                            ac[jt] = __builtin_amdgcn_mfma_f32_16x16x32_bf16(
                                ef, vf, ac[jt], 0, 0, 0);
                        }
                    __builtin_amdgcn_s_setprio(0);
                    if (k < 15) BARX;
                }
                // epilogue for this chunk
                // T1 + Tov: i masked (pos = c0 + it*16 + quad*4 + r),
                //           j = h*64 + w*16 + mr
                const int j1 = h * 64 + w * 16 + mr;
#pragma unroll
                for (int it = 0; it < 2; ++it)
                    if (it < ntc) {
#pragma unroll
                        for (int r = 0; r < 4; ++r) {
                            const int pos = c0 + it * 16 + quad * 4 + r;
                            if (pos < cnt) {
                                const int i = lrow[pos];
                                const float s = ar[it][r];
                                const float c = (i == j1) ? 1.0f
                                                          : tanhf(s + cb);
                                const float d = c - Ctb[i * Nx + j1];
                                T1 += d * d;
                                Tov += d * d * mloc[j1];
                            }
                        }
                    }
                // T2: i = h*64 + w*16 + quad*4 + r, j masked
                //     (pos = c0 + jt*16 + mr)
#pragma unroll
                for (int jt = 0; jt < 2; ++jt)
                    if (jt < ntc) {
                        const int pos = c0 + jt * 16 + mr;
                        const int valid = (pos < cnt);
                        const int j = lrow[pos & 127];
#pragma unroll
                        for (int r = 0; r < 4; ++r) {
                            if (valid) {
                                const int i = h * 64 + w * 16 + quad * 4 + r;
                                const float s = ac[jt][r];
                                const float c = (i == j) ? 1.0f
                                                         : tanhf(s + cb);
                                const float d = c - Ctb[i * Nx + j];
                                T2 += d * d;
                            }
                        }
                    }
#undef TSTAGE
            }
        }
        float lsum = T1 + T2 - Tov;
#pragma unroll
        for (int off = 32; off > 0; off >>= 1) lsum += __shfl_down(lsum, off);
        if (l == 0) redf[w][0] = lsum;
        __syncthreads();
        if (t == 0) {
            atomicAdd(&accs[2], redf[0][0] + redf[1][0] + redf[2][0] + redf[3][0]);
            if (h == 0) {
                const float c = (float)cnt;
                atomicAdd(&accs[3], 256.0f * c - c * c);   // per-batch n_me
            }
        }
    } else {
        // ---- head branch ----
        const int blk = blockIdx.x - 512;
        const int cnt = min(*cntp, CAP);
        float ce_acc = 0.0f, sse_acc = 0.0f;
        for (int idx = blk * 4 + w; idx < cnt; idx += 256 * 4) {
            const int r = list[idx];
            const uint4 ut = ((const uint4*)(Hc + (size_t)idx * 2048))[l];
            const uint4 us = ((const uint4*)(Hc + (size_t)idx * 2048 + 512))[l];
            float a[8], b8[8];
            {
                const unsigned uu[4] = {ut.x, ut.y, ut.z, ut.w};
                const unsigned vv[4] = {us.x, us.y, us.z, us.w};
#pragma unroll
                for (int j = 0; j < 4; ++j) {
                    a[2 * j]      = bf2f((unsigned short)(uu[j] & 0xffff));
                    a[2 * j + 1]  = bf2f((unsigned short)(uu[j] >> 16));
                    b8[2 * j]     = bf2f((unsigned short)(vv[j] & 0xffff));
                    b8[2 * j + 1] = bf2f((unsigned short)(vv[j] >> 16));
                }
            }
            float st = 0, qt = 0, ss = 0, qs = 0;
#pragma unroll
            for (int j = 0; j < 8; ++j) {
                st += a[j]; qt += a[j] * a[j];
                ss += b8[j]; qs += b8[j] * b8[j];
            }
#pragma unroll
            for (int off = 32; off > 0; off >>= 1) {
                st += __shfl_xor(st, off); qt += __shfl_xor(qt, off);
                ss += __shfl_xor(ss, off); qs += __shfl_xor(qs, off);
            }
            const float mt = st * (1.0f / Dx);
            const float rt = rsqrtf(qt * (1.0f / Dx) - mt * mt + LN_EPS);
            const float ms = ss * (1.0f / Dx);
            const float rs = rsqrtf(qs * (1.0f / Dx) - ms * ms + LN_EPS);

            const int c0 = l * 8;
            float tp[6] = {}, sp[8] = {};
#pragma unroll
            for (int j = 0; j < 8; ++j) {
                const int c = c0 + j;
                const float nt2 = (a[j] - mt) * rt * tg[c] + tbeta[c];
#pragma unroll
                for (int k = 0; k < 6; ++k) tp[k] += nt2 * tW2[c * 6 + k];
                const float ns = (b8[j] - ms) * rs * sg[c] + sbeta[c];
#pragma unroll
                for (int k = 0; k < 8; ++k) sp[k] += ns * sW2[c * 8 + k];
            }
#pragma unroll
            for (int k = 0; k < 6; ++k)
#pragma unroll
                for (int off = 32; off > 0; off >>= 1) tp[k] += __shfl_down(tp[k], off);
#pragma unroll
            for (int k = 0; k < 8; ++k)
#pragma unroll
                for (int off = 32; off > 0; off >>= 1) sp[k] += __shfl_down(sp[k], off);

            if (l == 0) {
                float lg[6];
#pragma unroll
                for (int k = 0; k < 6; ++k) lg[k] = tp[k] + tb2[k];
                float mx = lg[0];
#pragma unroll
                for (int k = 1; k < 6; ++k) mx = fmaxf(mx, lg[k]);
                float se = 0.0f;
#pragma unroll
                for (int k = 0; k < 6; ++k) se += expf(lg[k] - mx);
                ce_acc += -(lg[tgt[r & (Nx - 1)]] - mx - logf(se));
                float sse = 0.0f;
#pragma unroll
                for (int k = 0; k < 8; ++k) {
                    const float d = sp[k] + sb2[k] - stats[(size_t)r * NSTATS + k];
                    sse += d * d;
                }
                sse_acc += sse;
            }
        }
        if (l == 0) { redf[w][0] = ce_acc; redf[w][1] = sse_acc; }
        __syncthreads();
        if (t == 0) {
            atomicAdd(&accs[0], redf[0][0] + redf[1][0] + redf[2][0] + redf[3][0]);
            atomicAdd(&accs[1], redf[0][1] + redf[1][1] + redf[2][1] + redf[3][1]);
        }
    }
    // ---- arrival + final reduce (last of 768 blocks) ----
    __syncthreads();
    if (t == 0) {
        __threadfence();
        const int old = atomicAdd(done, 1);
        if (old == 767) {
            __threadfence();
            const float CE  = atomicAdd(&accs[0], 0.0f);
            const float SSE = atomicAdd(&accs[1], 0.0f);
            const float CO  = atomicAdd(&accs[2], 0.0f);
            const float ME  = atomicAdd(&accs[3], 0.0f);
            const float nm = fmaxf((float)min(*cntp, CAP), 1.0f);
            out[0] = CE / nm + SSE / (nm * (float)NSTATS) +
                     0.5f * CO / fmaxf(ME, 1.0f);
        }
    }
}

extern "C" void kernel_launch(void* const* d_in, const int* in_sizes, int n_in,
                              void* d_out, int out_size, void* d_ws, size_t ws_size,
                              hipStream_t stream) {
    const float* e      = (const float*)d_in[0];
    const int*   mcols  = (const int*)d_in[1];
    const int*   ttgt   = (const int*)d_in[2];
    const float* stats  = (const float*)d_in[3];
    const float* corrT  = (const float*)d_in[4];
    const float* tW1    = (const float*)d_in[5];
    const float* tb1    = (const float*)d_in[6];
    const float* tg     = (const float*)d_in[7];
    const float* tbeta  = (const float*)d_in[8];
    const float* tW2    = (const float*)d_in[9];
    const float* tb2    = (const float*)d_in[10];
    const float* sW1    = (const float*)d_in[11];
    const float* sb1    = (const float*)d_in[12];
    const float* sg     = (const float*)d_in[13];
    const float* sbeta  = (const float*)d_in[14];
    const float* sW2    = (const float*)d_in[15];
    const float* sb2    = (const float*)d_in[16];
    const float* cW     = (const float*)d_in[17];
    const float* cb     = (const float*)d_in[18];
    float* out = (float*)d_out;

    char* ws = (char*)d_ws;
    unsigned short* Eb    = (unsigned short*)(ws + EB_OFF);
    unsigned short* Hc    = (unsigned short*)(ws + HC_OFF);
    unsigned short* Wtcmb = (unsigned short*)(ws + WT_OFF);
    unsigned short* Wtc   = (unsigned short*)(ws + WTC_OFF);
    unsigned short* Wc    = (unsigned short*)(ws + WC_OFF);
    int*   list  = (int*)(ws + LIST_OFF);
    int*   cnts  = (int*)(ws + CNTS_OFF);
    int*   bases = (int*)(ws + BASES_OFF);
    int*   cntp  = (int*)(ws + CNTP_OFF);
    float* accs  = (float*)(ws + ACC_OFF);
    int*   done  = (int*)(ws + DONE_OFF);

    hipMemsetAsync(ws + CNTP_OFF, 0, 48, stream);
    k_prep<<<8704, 256, 0, stream>>>(e, tW1, sW1, cW, Eb, Wtcmb, Wtc, Wc,
                                     mcols, list, cnts, bases, cntp);
    k_gemms<<<512, 512, 0, stream>>>(Eb, Wtcmb, Wtc, Wc, tb1, sb1, Hc,
                                     list, cntp);
    k_tail<<<768, 256, 0, stream>>>(Eb, corrT, mcols, cb, Hc,
                                    tg, tbeta, tW2, tb2, sg, sbeta, sW2, sb2,
                                    list, cnts, bases, cntp, ttgt, stats,
                                    accs, done, out);
}

// Round 10
// 225.879 us; speedup vs baseline: 1.0719x; 1.0719x over previous
//
#include <hip/hip_runtime.h>
#include <math.h>

#define Bx 256
#define Nx 128
#define Dx 512
#define NTYPES 6
#define NSTATS 8
#define LN_EPS 1e-5f
#define CAP 8192          // max compacted masked rows (true ~4915)

typedef __attribute__((ext_vector_type(8))) short frag8;   // 8 bf16 (4 VGPRs)
typedef __attribute__((ext_vector_type(4))) float f32x4;   // 4 fp32 acc

__device__ __forceinline__ unsigned short f2bf(float f) {
    unsigned u = __float_as_uint(f);
    u += 0x7fff + ((u >> 16) & 1);   // RNE
    return (unsigned short)(u >> 16);
}
__device__ __forceinline__ float bf2f(unsigned short s) {
    return __uint_as_float((unsigned)s << 16);
}

#define ASYNC16(g, l) __builtin_amdgcn_global_load_lds(                      \
    (const __attribute__((address_space(1))) void*)(g),                      \
    (__attribute__((address_space(3))) void*)(l), 16, 0, 0)

#define VWAIT(NIMM)                                                          \
    asm volatile("s_waitcnt vmcnt(" #NIMM ")" ::: "memory");                 \
    __builtin_amdgcn_sched_barrier(0);
#define BARX __builtin_amdgcn_s_barrier();

// ws layout (bytes)
#define EB_OFF    0ULL          // Eb  bf16 [32768][512]   32 MB
#define HC_OFF    33554432ULL   // Hc  bf16 [CAP][2048]    32 MB (heads|U_m|V_m)
#define WT_OFF    67108864ULL   // Wtcmb bf16 [1024][512]   1 MB
#define WTC_OFF   68157440ULL   // Wtc bf16 [512][512]    0.5 MB (= cW^T rows)
#define WC_OFF    68681728ULL   // Wc  bf16 [512][512]    0.5 MB (= cW rows)
#define LIST_OFF  69206016ULL   // int[CAP]
#define CNTS_OFF  69238784ULL   // int[256]
#define BASES_OFF 69239808ULL   // int[256]
#define CNTP_OFF  69240832ULL   // int   (memset region starts here, 48 B)
#define ACC_OFF   69240848ULL   // float[4]: CE, SSE, CO, ME
#define DONE_OFF  69240864ULL   // int arrival counter

// Mega-prep, one dispatch:
// blocks [0,256):    per-batch mask compaction -> list/cnts/bases/cntp
// blocks [256,448):  3 weight transposes via coalesced LDS 64x64 tiles
// blocks [448,512):  straight convert cW f32 -> bf16 row-major (Wc)
// blocks [512,8704): E f32 -> bf16 (wave per row, 4 rows/block)
__global__ __launch_bounds__(256) void k_prep(
    const float* __restrict__ e, const float* __restrict__ W0,
    const float* __restrict__ W1, const float* __restrict__ W2,
    unsigned short* __restrict__ Eb, unsigned short* __restrict__ Tcmb,
    unsigned short* __restrict__ Tc, unsigned short* __restrict__ Wc,
    const int* __restrict__ m, int* __restrict__ list,
    int* __restrict__ cnts, int* __restrict__ bases, int* cntp) {
    const int bid = blockIdx.x;
    const int t = threadIdx.x;
    if (bid < 256) {
        const int b = bid;
        const int r = b * Nx + t;
        int v = 0;
        if (t < 128) v = (m[r] != 0) ? 1 : 0;
        const unsigned long long bal = __ballot(v);
        const int wid = t >> 6, lane = t & 63;
        __shared__ int wcnt[2];
        __shared__ int base;
        if (lane == 0 && wid < 2) wcnt[wid] = __popcll(bal);
        __syncthreads();
        const int cnt = wcnt[0] + wcnt[1];
        if (t == 0) {
            base = atomicAdd(cntp, cnt);
            cnts[b] = cnt;
            bases[b] = base;
        }
        __syncthreads();
        if (t < 128 && v) {
            const int rank = __popcll(bal & ((1ULL << lane) - 1)) +
                             (wid ? wcnt[0] : 0);
            const int p = base + rank;
            if (p < CAP) list[p] = r;
        }
        return;
    }
    if (bid < 448) {
        const int lin = bid - 256;          // 0..191
        const int mid = lin >> 6;           // matrix 0..2 (tW1, sW1, cW)
        const int tl  = lin & 63;
        const int ti = tl >> 3, tj = tl & 7;
        const float* W = (mid == 0) ? W0 : (mid == 1) ? W1 : W2;
        unsigned short* T = (mid == 2) ? Tc : (Tcmb + mid * 262144);
        __shared__ float sh[64][65];
        const int c = t & 63;
        const int r4 = t >> 6;
#pragma unroll
        for (int rr = 0; rr < 16; ++rr) {
            const int row = rr * 4 + r4;
            sh[row][c] = W[(size_t)(ti * 64 + row) * Dx + tj * 64 + c];
        }
        __syncthreads();
#pragma unroll
        for (int rr = 0; rr < 16; ++rr) {
            const int col2 = rr * 4 + r4;
            T[(size_t)(tj * 64 + col2) * Dx + ti * 64 + c] = f2bf(sh[c][col2]);
        }
        return;
    }
    if (bid < 512) {
        // cW f32 -> bf16 row-major (B-rows for V_m = E @ cW^T)
        const int base = (bid - 448) * 4096 + t * 16;
        const float4* src = (const float4*)(W2 + base);
        unsigned short o[16];
#pragma unroll
        for (int q = 0; q < 4; ++q) {
            const float4 v = src[q];
            o[q * 4 + 0] = f2bf(v.x); o[q * 4 + 1] = f2bf(v.y);
            o[q * 4 + 2] = f2bf(v.z); o[q * 4 + 3] = f2bf(v.w);
        }
        *(uint4*)(Wc + base) = *(const uint4*)(o);
        *(uint4*)(Wc + base + 8) = *(const uint4*)(o + 8);
        return;
    }
    const int r = (bid - 512) * 4 + (t >> 6);
    const int lane = t & 63;
    const float4* src = (const float4*)(e + (size_t)r * Dx);
    const float4 a = src[lane * 2];
    const float4 b = src[lane * 2 + 1];
    unsigned short u[8] = {f2bf(a.x), f2bf(a.y), f2bf(a.z), f2bf(a.w),
                           f2bf(b.x), f2bf(b.y), f2bf(b.z), f2bf(b.w)};
    ((uint4*)(Eb + (size_t)r * Dx))[lane] = *(const uint4*)u;
}

// Combined masked GEMM: Hc[pos][0:2048] =
//   [ GELU(E[list[pos]] @ Wtcmb^T + bias) | E[list] @ cW | E[list] @ cW^T ]
// 128x256 tiles, 512 threads (8 waves of 64x64), BK=32, counted-vmcnt dbuf.
__global__ __launch_bounds__(512) void k_gemms(
    const unsigned short* __restrict__ Eb,
    const unsigned short* __restrict__ Wtcmb,
    const unsigned short* __restrict__ Wtc,
    const unsigned short* __restrict__ Wc,
    const float* __restrict__ bias0, const float* __restrict__ bias1,
    unsigned short* __restrict__ Hc,
    const int* __restrict__ list, const int* __restrict__ cntp) {
    __shared__ unsigned short As[2 * 4096];   // 2 x [128][32] bf16
    __shared__ unsigned short Bs[2 * 8192];   // 2 x [256][32] bf16
    const int bid = blockIdx.x;
    const int t = threadIdx.x;
    const int cnt = min(*cntp, CAP);
    const int rt = ((bid >> 6) << 3) | (bid & 7);   // XCD-swizzled row tile
    const int row0 = rt << 7;
    if (row0 >= cnt) return;
    const int ct = (bid >> 3) & 7;
    const int col0 = ct << 8;
    // Bbase already includes the 256-col panel offset.
    const unsigned short* Bbase =
        (ct < 4) ? (Wtcmb + (size_t)ct * 256 * Dx)
      : (ct < 6) ? (Wtc + (size_t)(ct - 4) * 256 * Dx)
                 : (Wc + (size_t)(ct - 6) * 256 * Dx);
    const int kq = (t & 3) ^ ((t >> 3) & 3);
    const int ra = list[min(row0 + (t >> 2), cnt - 1)];
    const unsigned short* pA = Eb + (size_t)ra * Dx + kq * 8;
    const unsigned short* pB0 = Bbase + (size_t)(t >> 2) * Dx + kq * 8;
    const unsigned short* pB1 = pB0 + (size_t)128 * Dx;
    const int w = t >> 6, l = t & 63;
    const int wr = (w >> 2) * 64, wcol = (w & 3) * 64;
    const int quad = l >> 4, mr = l & 15;
    const int co = (quad ^ ((mr >> 1) & 3)) * 8;

#define MSTAGE(bf, k0)                                                       \
  { ASYNC16(pA + (k0), As + (bf) * 4096 + t * 8);                            \
    ASYNC16(pB0 + (k0), Bs + (bf) * 8192 + t * 8);                           \
    ASYNC16(pB1 + (k0), Bs + (bf) * 8192 + 4096 + t * 8); }

    f32x4 acc[4][4] = {};
    MSTAGE(0, 0);
    int buf = 0;
    for (int k = 0; k < 16; ++k) {
        if (k < 15) { MSTAGE(buf ^ 1, (k + 1) * 32); VWAIT(3); }
        else        { VWAIT(0); }
        BARX;
        frag8 af[4], bfv[4];
#pragma unroll
        for (int i = 0; i < 4; ++i)
            af[i] = *(const frag8*)&As[buf * 4096 + (wr + i * 16 + mr) * 32 + co];
#pragma unroll
        for (int j = 0; j < 4; ++j)
            bfv[j] = *(const frag8*)&Bs[buf * 8192 + (wcol + j * 16 + mr) * 32 + co];
        __builtin_amdgcn_s_setprio(1);
#pragma unroll
        for (int i = 0; i < 4; ++i)
#pragma unroll
            for (int j = 0; j < 4; ++j)
                acc[i][j] = __builtin_amdgcn_mfma_f32_16x16x32_bf16(
                    af[i], bfv[j], acc[i][j], 0, 0, 0);
        __builtin_amdgcn_s_setprio(0);
        if (k < 15) BARX;
        buf ^= 1;
    }
#pragma unroll
    for (int i = 0; i < 4; ++i)
#pragma unroll
        for (int j = 0; j < 4; ++j)
#pragma unroll
            for (int r = 0; r < 4; ++r) {
                const int row = row0 + wr + i * 16 + quad * 4 + r;
                const int col = col0 + wcol + j * 16 + mr;
                float v = acc[i][j][r];
                if (col < 1024) {
                    v += (col < 512) ? bias0[col] : bias1[col - 512];
                    v = 0.5f * v * (1.0f + erff(v * 0.70710678118654752f));
                }
                Hc[(size_t)row * 2048 + col] = f2bf(v);
            }
#undef MSTAGE
}

// Tail, one dispatch (grid 512):
// blocks [0,256):   per-batch corr, chunked U/V (32 rows), BK=64:
//                   8 K-iters (half of r8's 16 -> half the barrier/wait
//                   latency chain, which r8/r9 showed is the block's cost).
//                   E tile [128][64], U/V [32][64], 8-slot XOR swizzle.
// blocks [256,512): MLP heads: LN + W2 + CE/MSE over compact list
__global__ __launch_bounds__(256) void k_tail(
    const unsigned short* __restrict__ Eb,
    const float* __restrict__ Ct, const int* __restrict__ m,
    const float* __restrict__ cbp,
    const unsigned short* __restrict__ Hc,
    const float* __restrict__ tg, const float* __restrict__ tbeta,
    const float* __restrict__ tW2, const float* __restrict__ tb2,
    const float* __restrict__ sg, const float* __restrict__ sbeta,
    const float* __restrict__ sW2, const float* __restrict__ sb2,
    const int* __restrict__ list, const int* __restrict__ cnts,
    const int* __restrict__ bases, const int* __restrict__ cntp,
    const int* __restrict__ tgt, const float* __restrict__ stats,
    float* __restrict__ accs, int* __restrict__ done,
    float* __restrict__ out) {
    __shared__ unsigned short Elds[2 * 8192];   // 2 x [128][64] bf16
    __shared__ unsigned short Ulds[2 * 2048];   // 2 x [32][64] bf16
    __shared__ unsigned short Vlds[2 * 2048];
    __shared__ float mloc[128];
    __shared__ int lrow[128];
    __shared__ float redf[4][2];
    const int t = threadIdx.x;
    const int w = t >> 6, l = t & 63;
    const int quad = l >> 4, mr = l & 15;

    if (blockIdx.x < 256) {
        const int b = blockIdx.x;
        const int cnt = cnts[b];
        const int cbase = bases[b];
        if (t < 128) {
            mloc[t] = (m[b * Nx + t] != 0) ? 1.0f : 0.0f;
            lrow[t] = (t < cnt) ? (list[cbase + t] & (Nx - 1)) : 0;
        }
        __syncthreads();
        float T1 = 0.0f, T2 = 0.0f, Tov = 0.0f;
        const float cb = cbp[0];
        const float* Ctb = Ct + (size_t)b * Nx * Nx;
        if (cnt > 0) {
            // E [128][64]: 4 rounds of 32 rows; round q: row = q*32 + (t>>3),
            // slot t&7 holds global chunk (t&7)^((row>>1)&7) = (t&7)^((t>>4)&7)
            const int kqE = (t & 7) ^ ((t >> 4) & 7);
            const size_t rb = (size_t)b * Nx;
            const unsigned short* pE0 = Eb + (rb + (t >> 3)) * Dx + kqE * 8;
            const unsigned short* pE1 = Eb + (rb + 32 + (t >> 3)) * Dx + kqE * 8;
            const unsigned short* pE2 = Eb + (rb + 64 + (t >> 3)) * Dx + kqE * 8;
            const unsigned short* pE3 = Eb + (rb + 96 + (t >> 3)) * Dx + kqE * 8;
            // U/V [32][64]: waves 0-1 stage U, waves 2-3 stage V; 2 rounds of
            // 16 rows each; round q: row = q*16 + (t2>>3); kq2 invariant of q
            const int hw = t >> 7;
            const int t2 = t & 127;
            const int kq2 = (t2 & 7) ^ ((t2 >> 4) & 7);

            for (int c0 = 0; c0 < cnt; c0 += 32) {
                const int ntc = min(((cnt - c0) + 15) >> 4, 2);
                const int ur0 = min(c0 + (t2 >> 3), cnt - 1);
                const int ur1 = min(c0 + 16 + (t2 >> 3), cnt - 1);
                const unsigned short* pUV0 = Hc + (size_t)(cbase + ur0) * 2048
                                             + (hw ? 1536 : 1024) + kq2 * 8;
                const unsigned short* pUV1 = Hc + (size_t)(cbase + ur1) * 2048
                                             + (hw ? 1536 : 1024) + kq2 * 8;
                unsigned short* UVdst = hw ? Vlds : Ulds;

#define TSTAGE(bf, ph)                                                       \
  { ASYNC16(pE0 + (ph) * 64, Elds + (bf) * 8192 + t * 8);                    \
    ASYNC16(pE1 + (ph) * 64, Elds + (bf) * 8192 + 2048 + t * 8);             \
    ASYNC16(pE2 + (ph) * 64, Elds + (bf) * 8192 + 4096 + t * 8);             \
    ASYNC16(pE3 + (ph) * 64, Elds + (bf) * 8192 + 6144 + t * 8);             \
    ASYNC16(pUV0 + (ph) * 64, UVdst + (bf) * 2048 + t2 * 8);                 \
    ASYNC16(pUV1 + (ph) * 64, UVdst + (bf) * 2048 + 1024 + t2 * 8); }

                f32x4 ar[2][2] = {};   // [i-tile in chunk][E j-frag]
                f32x4 ac[2][2] = {};   // [E i-frag][j-tile in chunk]
                TSTAGE(0, 0);
                int buf = 0;
                for (int k = 0; k < 8; ++k) {
                    if (k < 7) { TSTAGE(buf ^ 1, k + 1); VWAIT(6); }
                    else       { VWAIT(0); }
                    BARX;
#pragma unroll
                    for (int ks = 0; ks < 2; ++ks) {
                        const int co = ((ks * 4 + quad) ^ ((mr >> 1) & 7)) * 8;
                        frag8 ef[2];
#pragma unroll
                        for (int eidx = 0; eidx < 2; ++eidx)
                            ef[eidx] = *(const frag8*)&Elds[buf * 8192 +
                                (w * 32 + eidx * 16 + mr) * 64 + co];
                        __builtin_amdgcn_s_setprio(1);
#pragma unroll
                        for (int it = 0; it < 2; ++it)
                            if (it < ntc) {
                                const frag8 uf = *(const frag8*)&Ulds[
                                    buf * 2048 + (it * 16 + mr) * 64 + co];
                                ar[it][0] = __builtin_amdgcn_mfma_f32_16x16x32_bf16(
                                    uf, ef[0], ar[it][0], 0, 0, 0);
                                ar[it][1] = __builtin_amdgcn_mfma_f32_16x16x32_bf16(
                                    uf, ef[1], ar[it][1], 0, 0, 0);
                            }
#pragma unroll
                        for (int jt = 0; jt < 2; ++jt)
                            if (jt < ntc) {
                                const frag8 vf = *(const frag8*)&Vlds[
                                    buf * 2048 + (jt * 16 + mr) * 64 + co];
                                ac[0][jt] = __builtin_amdgcn_mfma_f32_16x16x32_bf16(
                                    ef[0], vf, ac[0][jt], 0, 0, 0);
                                ac[1][jt] = __builtin_amdgcn_mfma_f32_16x16x32_bf16(
                                    ef[1], vf, ac[1][jt], 0, 0, 0);
                            }
                        __builtin_amdgcn_s_setprio(0);
                    }
                    if (k < 7) BARX;
                    buf ^= 1;
                }
                // epilogue for this chunk
                // T1 + Tov: i masked (pos = c0 + it*16 + quad*4 + r),
                //           j = w*32 + eidx*16 + mr
#pragma unroll
                for (int it = 0; it < 2; ++it)
                    if (it < ntc) {
#pragma unroll
                        for (int eidx = 0; eidx < 2; ++eidx) {
                            const int j = w * 32 + eidx * 16 + mr;
#pragma unroll
                            for (int r = 0; r < 4; ++r) {
                                const int pos = c0 + it * 16 + quad * 4 + r;
                                if (pos < cnt) {
                                    const int i = lrow[pos];
                                    const float s = ar[it][eidx][r];
                                    const float c = (i == j) ? 1.0f
                                                             : tanhf(s + cb);
                                    const float d = c - Ctb[i * Nx + j];
                                    T1 += d * d;
                                    Tov += d * d * mloc[j];
                                }
                            }
                        }
                    }
                // T2: i = w*32 + eidx*16 + quad*4 + r, j masked
                //     (pos = c0 + jt*16 + mr)
#pragma unroll
                for (int jt = 0; jt < 2; ++jt)
                    if (jt < ntc) {
                        const int pos = c0 + jt * 16 + mr;
                        const int valid = (pos < cnt);
                        const int j = lrow[pos & 127];
#pragma unroll
                        for (int eidx = 0; eidx < 2; ++eidx) {
#pragma unroll
                            for (int r = 0; r < 4; ++r) {
                                if (valid) {
                                    const int i = w * 32 + eidx * 16 +
                                                  quad * 4 + r;
                                    const float s = ac[eidx][jt][r];
                                    const float c = (i == j) ? 1.0f
                                                             : tanhf(s + cb);
                                    const float d = c - Ctb[i * Nx + j];
                                    T2 += d * d;
                                }
                            }
                        }
                    }
#undef TSTAGE
            }
        }
        float lsum = T1 + T2 - Tov;
#pragma unroll
        for (int off = 32; off > 0; off >>= 1) lsum += __shfl_down(lsum, off);
        if (l == 0) redf[w][0] = lsum;
        __syncthreads();
        if (t == 0) {
            atomicAdd(&accs[2], redf[0][0] + redf[1][0] + redf[2][0] + redf[3][0]);
            const float c = (float)cnt;
            atomicAdd(&accs[3], 256.0f * c - c * c);   // per-batch n_me
        }
    } else {
        // ---- head branch ----
        const int blk = blockIdx.x - 256;
        const int cnt = min(*cntp, CAP);
        float ce_acc = 0.0f, sse_acc = 0.0f;
        for (int idx = blk * 4 + w; idx < cnt; idx += 256 * 4) {
            const int r = list[idx];
            const uint4 ut = ((const uint4*)(Hc + (size_t)idx * 2048))[l];
            const uint4 us = ((const uint4*)(Hc + (size_t)idx * 2048 + 512))[l];
            float a[8], b8[8];
            {
                const unsigned uu[4] = {ut.x, ut.y, ut.z, ut.w};
                const unsigned vv[4] = {us.x, us.y, us.z, us.w};
#pragma unroll
                for (int j = 0; j < 4; ++j) {
                    a[2 * j]      = bf2f((unsigned short)(uu[j] & 0xffff));
                    a[2 * j + 1]  = bf2f((unsigned short)(uu[j] >> 16));
                    b8[2 * j]     = bf2f((unsigned short)(vv[j] & 0xffff));
                    b8[2 * j + 1] = bf2f((unsigned short)(vv[j] >> 16));
                }
            }
            float st = 0, qt = 0, ss = 0, qs = 0;
#pragma unroll
            for (int j = 0; j < 8; ++j) {
                st += a[j]; qt += a[j] * a[j];
                ss += b8[j]; qs += b8[j] * b8[j];
            }
#pragma unroll
            for (int off = 32; off > 0; off >>= 1) {
                st += __shfl_xor(st, off); qt += __shfl_xor(qt, off);
                ss += __shfl_xor(ss, off); qs += __shfl_xor(qs, off);
            }
            const float mt = st * (1.0f / Dx);
            const float rt = rsqrtf(qt * (1.0f / Dx) - mt * mt + LN_EPS);
            const float ms = ss * (1.0f / Dx);
            const float rs = rsqrtf(qs * (1.0f / Dx) - ms * ms + LN_EPS);

            const int c0 = l * 8;
            float tp[6] = {}, sp[8] = {};
#pragma unroll
            for (int j = 0; j < 8; ++j) {
                const int c = c0 + j;
                const float nt2 = (a[j] - mt) * rt * tg[c] + tbeta[c];
#pragma unroll
                for (int k = 0; k < 6; ++k) tp[k] += nt2 * tW2[c * 6 + k];
                const float ns = (b8[j] - ms) * rs * sg[c] + sbeta[c];
#pragma unroll
                for (int k = 0; k < 8; ++k) sp[k] += ns * sW2[c * 8 + k];
            }
#pragma unroll
            for (int k = 0; k < 6; ++k)
#pragma unroll
                for (int off = 32; off > 0; off >>= 1) tp[k] += __shfl_down(tp[k], off);
#pragma unroll
            for (int k = 0; k < 8; ++k)
#pragma unroll
                for (int off = 32; off > 0; off >>= 1) sp[k] += __shfl_down(sp[k], off);

            if (l == 0) {
                float lg[6];
#pragma unroll
                for (int k = 0; k < 6; ++k) lg[k] = tp[k] + tb2[k];
                float mx = lg[0];
#pragma unroll
                for (int k = 1; k < 6; ++k) mx = fmaxf(mx, lg[k]);
                float se = 0.0f;
#pragma unroll
                for (int k = 0; k < 6; ++k) se += expf(lg[k] - mx);
                ce_acc += -(lg[tgt[r & (Nx - 1)]] - mx - logf(se));
                float sse = 0.0f;
#pragma unroll
                for (int k = 0; k < 8; ++k) {
                    const float d = sp[k] + sb2[k] - stats[(size_t)r * NSTATS + k];
                    sse += d * d;
                }
                sse_acc += sse;
            }
        }
        if (l == 0) { redf[w][0] = ce_acc; redf[w][1] = sse_acc; }
        __syncthreads();
        if (t == 0) {
            atomicAdd(&accs[0], redf[0][0] + redf[1][0] + redf[2][0] + redf[3][0]);
            atomicAdd(&accs[1], redf[0][1] + redf[1][1] + redf[2][1] + redf[3][1]);
        }
    }
    // ---- arrival + final reduce (last of 512 blocks) ----
    __syncthreads();
    if (t == 0) {
        __threadfence();
        const int old = atomicAdd(done, 1);
        if (old == 511) {
            __threadfence();
            const float CE  = atomicAdd(&accs[0], 0.0f);
            const float SSE = atomicAdd(&accs[1], 0.0f);
            const float CO  = atomicAdd(&accs[2], 0.0f);
            const float ME  = atomicAdd(&accs[3], 0.0f);
            const float nm = fmaxf((float)min(*cntp, CAP), 1.0f);
            out[0] = CE / nm + SSE / (nm * (float)NSTATS) +
                     0.5f * CO / fmaxf(ME, 1.0f);
        }
    }
}

extern "C" void kernel_launch(void* const* d_in, const int* in_sizes, int n_in,
                              void* d_out, int out_size, void* d_ws, size_t ws_size,
                              hipStream_t stream) {
    const float* e      = (const float*)d_in[0];
    const int*   mcols  = (const int*)d_in[1];
    const int*   ttgt   = (const int*)d_in[2];
    const float* stats  = (const float*)d_in[3];
    const float* corrT  = (const float*)d_in[4];
    const float* tW1    = (const float*)d_in[5];
    const float* tb1    = (const float*)d_in[6];
    const float* tg     = (const float*)d_in[7];
    const float* tbeta  = (const float*)d_in[8];
    const float* tW2    = (const float*)d_in[9];
    const float* tb2    = (const float*)d_in[10];
    const float* sW1    = (const float*)d_in[11];
    const float* sb1    = (const float*)d_in[12];
    const float* sg     = (const float*)d_in[13];
    const float* sbeta  = (const float*)d_in[14];
    const float* sW2    = (const float*)d_in[15];
    const float* sb2    = (const float*)d_in[16];
    const float* cW     = (const float*)d_in[17];
    const float* cb     = (const float*)d_in[18];
    float* out = (float*)d_out;

    char* ws = (char*)d_ws;
    unsigned short* Eb    = (unsigned short*)(ws + EB_OFF);
    unsigned short* Hc    = (unsigned short*)(ws + HC_OFF);
    unsigned short* Wtcmb = (unsigned short*)(ws + WT_OFF);
    unsigned short* Wtc   = (unsigned short*)(ws + WTC_OFF);
    unsigned short* Wc    = (unsigned short*)(ws + WC_OFF);
    int*   list  = (int*)(ws + LIST_OFF);
    int*   cnts  = (int*)(ws + CNTS_OFF);
    int*   bases = (int*)(ws + BASES_OFF);
    int*   cntp  = (int*)(ws + CNTP_OFF);
    float* accs  = (float*)(ws + ACC_OFF);
    int*   done  = (int*)(ws + DONE_OFF);

    hipMemsetAsync(ws + CNTP_OFF, 0, 48, stream);
    k_prep<<<8704, 256, 0, stream>>>(e, tW1, sW1, cW, Eb, Wtcmb, Wtc, Wc,
                                     mcols, list, cnts, bases, cntp);
    k_gemms<<<512, 512, 0, stream>>>(Eb, Wtcmb, Wtc, Wc, tb1, sb1, Hc,
                                     list, cntp);
    k_tail<<<512, 256, 0, stream>>>(Eb, corrT, mcols, cb, Hc,
                                    tg, tbeta, tW2, tb2, sg, sbeta, sW2, sb2,
                                    list, cnts, bases, cntp, ttgt, stats,
                                    accs, done, out);
}